// Round 13
// baseline (174.245 us; speedup 1.0000x reference)
//
#include <hip/hip_runtime.h>

// FractalAttention on gfx950: bf16 MFMA pipeline.
// cvt(fp32->bf16, fused) -> GEMM QKV (64x128 tile, 6/CU; epilogue: Q prescaled,
// K [h][s][d], V frag-packed) -> flash attention (32q/wave, grid 1024 = 4
// blocks/CU, K-only LDS, V direct-global frag-packed, no max-tracking,
// setprio) -> GEMM O-proj (64x128, 2/CU).

typedef unsigned short u16;
typedef unsigned int u32;
typedef __attribute__((ext_vector_type(8))) short short8;
typedef __attribute__((ext_vector_type(4))) float f32x4;
typedef __attribute__((ext_vector_type(4))) u16 u16x4;
typedef __attribute__((ext_vector_type(4))) u32 u32x4;

#define KDIM 1024
// 0.125 (1/sqrt(64)) * log2(e): fold softmax scale + base-2 conversion into Q
#define QSCALE 0.18033688011112042f
// log2(phi)
#define LOG2PHI 0.6942419136306174f

__device__ __forceinline__ u16 f2bf(float f) {
  u32 u = __builtin_bit_cast(u32, f);
  u32 r = (u + 0x7fffu + ((u >> 16) & 1u)) >> 16;  // RNE
  return (u16)r;
}

__device__ __forceinline__ u32 cvtpk(float lo, float hi) {
  u32 r;
  asm("v_cvt_pk_bf16_f32 %0, %1, %2" : "=v"(r) : "v"(lo), "v"(hi));
  return r;
}

// single v_exp_f32 (exp2f without fast-math lowers to ~8 instrs of ocml fixup)
#define EXP2(x) __builtin_amdgcn_exp2f(x)

__device__ __forceinline__ f32x4 fzero() {
  f32x4 z; z[0] = 0.f; z[1] = 0.f; z[2] = 0.f; z[3] = 0.f; return z;
}

// ---------------- fused fp32 -> bf16 convert (x + 4 weight matrices) ----------------
__global__ __launch_bounds__(256) void cvt_all(
    const float* __restrict__ x, const float* __restrict__ wq,
    const float* __restrict__ wk, const float* __restrict__ wv,
    const float* __restrict__ wo, u16* __restrict__ xb,
    u16* __restrict__ wqkv, u16* __restrict__ wob) {
  const int i = blockIdx.x * 256 + threadIdx.x;
  const float* src;
  u16* dst;
  int off;
  if (i < 1048576) { src = x; dst = xb; off = i; }
  else if (i < 1310720) { src = wq; dst = wqkv; off = i - 1048576; }
  else if (i < 1572864) { src = wk; dst = wqkv + 1048576; off = i - 1310720; }
  else if (i < 1835008) { src = wv; dst = wqkv + 2097152; off = i - 1572864; }
  else { src = wo; dst = wob; off = i - 1835008; }
  f32x4 v = *(const f32x4*)(src + (size_t)off * 4);
  u16x4 o;
  o[0] = f2bf(v[0]); o[1] = f2bf(v[1]); o[2] = f2bf(v[2]); o[3] = f2bf(v[3]);
  *(u16x4*)(dst + (size_t)off * 4) = o;
}

// ---------------- GEMM C = A[M,1024] * B[N,1024]^T (both K-major bf16) ----------------
// MB x 128 tile, BK=64, 4 waves (2x2), each wave (MB/2) x 64 via (MB/32)x4 frags.
// MODE 0: QKV epilogue. MODE 1: fp32 out + bias.
template <int MODE, int MB>
__global__ __launch_bounds__(256) void gemm_bt(
    const u16* __restrict__ A, const u16* __restrict__ Bw,
    const float* __restrict__ bias0, const float* __restrict__ bias1,
    const float* __restrict__ bias2,
    u16* __restrict__ qo, u16* __restrict__ ko, u16* __restrict__ vto,
    float* __restrict__ co) {
  __shared__ u16 As[MB * 64];
  __shared__ u16 Bs[128 * 64];
  const int tid = threadIdx.x;
  const int w = tid >> 6, lane = tid & 63;
  const int wr = w >> 1, wc = w & 1;
  const int bm = blockIdx.x, bn = blockIdx.y;
  const int lr = lane & 15, lg = lane >> 4;
  const int srow8 = lane >> 3;   // staging: row within 8-row group
  const int schunk = lane & 7;   // staging: 16B chunk within row
  constexpr int MF = MB / 32;    // A-frags per wave

  f32x4 acc[MF][4];
#pragma unroll
  for (int m = 0; m < MF; ++m)
#pragma unroll
    for (int n = 0; n < 4; ++n) acc[m][n] = fzero();

  for (int kt = 0; kt < KDIM / 64; ++kt) {
    // ---- stage A (MB rows) + B (128 rows): global_load_lds width16, source
    // pre-swizzled (c&7)^(row&7) so swizzled reads see logical layout (rule 21).
#pragma unroll
    for (int it = 0; it < MF; ++it) {
      const int g = w * MF + it;                       // 8-row group, 0..MB/8-1
      const int rowt = g * 8 + srow8;
      const int ck = schunk ^ (rowt & 7);
      const u16* sa = A + (size_t)(bm * MB + rowt) * KDIM + kt * 64 + ck * 8;
      __builtin_amdgcn_global_load_lds(
          (const __attribute__((address_space(1))) u32*)sa,
          (__attribute__((address_space(3))) u32*)&As[g * 512], 16, 0, 0);
    }
#pragma unroll
    for (int it = 0; it < 4; ++it) {
      const int g = w * 4 + it;                        // 0..15
      const int rowt = g * 8 + srow8;
      const int ck = schunk ^ (rowt & 7);
      const u16* sb = Bw + (size_t)(bn * 128 + rowt) * KDIM + kt * 64 + ck * 8;
      __builtin_amdgcn_global_load_lds(
          (const __attribute__((address_space(1))) u32*)sb,
          (__attribute__((address_space(3))) u32*)&Bs[g * 512], 16, 0, 0);
    }
    __syncthreads();
#pragma unroll
    for (int kk = 0; kk < 2; ++kk) {
      short8 af[MF], bf[4];
#pragma unroll
      for (int m = 0; m < MF; ++m) {
        const int row = wr * (MB / 2) + m * 16 + lr;
        const int kb = kk * 64 + lg * 16;
        af[m] = *(const short8*)((const char*)As + row * 128 + (kb ^ ((row & 7) << 4)));
      }
#pragma unroll
      for (int n = 0; n < 4; ++n) {
        const int row = wc * 64 + n * 16 + lr;
        const int kb = kk * 64 + lg * 16;
        bf[n] = *(const short8*)((const char*)Bs + row * 128 + (kb ^ ((row & 7) << 4)));
      }
#pragma unroll
      for (int m = 0; m < MF; ++m)
#pragma unroll
        for (int n = 0; n < 4; ++n)
          acc[m][n] = __builtin_amdgcn_mfma_f32_16x16x32_bf16(af[m], bf[n], acc[m][n], 0, 0, 0);
    }
    __syncthreads();
  }

  // ---- epilogue; C/D layout: row=(lane>>4)*4+reg, col=lane&15
#pragma unroll
  for (int m = 0; m < MF; ++m) {
#pragma unroll
    for (int n = 0; n < 4; ++n) {
#pragma unroll
      for (int r = 0; r < 4; ++r) {
        const int srow = bm * MB + wr * (MB / 2) + m * 16 + lg * 4 + r;
        const int col = bn * 128 + wc * 64 + n * 16 + lr;
        float v = acc[m][n][r];
        if (MODE == 0) {
          const int which = col >> 10;        // 0=q 1=k 2=v
          const int hd = col & 1023;
          const int h = hd >> 6, d = hd & 63;
          const float* bp = (which == 0) ? bias0 : (which == 1) ? bias1 : bias2;
          v += bp[hd];
          if (which == 0) {
            qo[(size_t)h * 262144 + (size_t)srow * 64 + d] = f2bf(v * QSCALE);
          } else if (which == 1) {
            ko[(size_t)h * 262144 + (size_t)srow * 64 + d] = f2bf(v);
          } else {
            // V frag-packed for attention's direct coalesced A-frag loads
            // (verified R6): element (key s, dim d) -> 32-key block blk32=s>>5,
            // k-slot kb5 = lg*8 + ki*4 + r (kappa of in-lane P order),
            // lane2 = (kb5>>3)*16 + (d&15), elem e = kb5&7, chunk dg = d>>4.
            const int k5 = srow & 31;
            const int kb5 = ((k5 >> 2) & 3) * 8 + ((k5 >> 4) & 1) * 4 + (k5 & 3);
            const int lane2 = (kb5 >> 3) * 16 + (d & 15);
            vto[((size_t)h * 128 + (srow >> 5)) * 2048 + (d >> 4) * 512 +
                lane2 * 8 + (kb5 & 7)] = f2bf(v);
          }
        } else {
          co[(size_t)srow * 1024 + col] = v + bias0[col];
        }
      }
    }
  }
}

// ---------------- flash attention v10: 32q/wave, 4 blocks/CU ----------------
// grid = 1024 blocks (XCD-swizzled): (h, qt) with 64 q-rows per block.
// 4 waves: qsub = w>>1 (which 32 q), kh = w&1 (which 2048-key half).
// K double-buffered in LDS (32KB, shared per kh); V loaded DIRECT from global
// in frag-packed layout (8 coalesced 1KB bursts per iter, R6-verified).
// No-max softmax (p=exp2(s), shift-invariant, logits bounded); key halves
// combined through retired K-staging LDS.
__global__ __launch_bounds__(256) void attn_kernel(const u16* __restrict__ Q,
                                                   const u16* __restrict__ K,
                                                   const u16* __restrict__ VT,
                                                   u16* __restrict__ O) {
  __shared__ u16 Ks[2][2][4096];  // [khalf][buf][64 keys x 64 d] = 32KB
  __shared__ float cL[64];        // combine: per-q lsum of kh=1
  const int tid = threadIdx.x;
  const int w = tid >> 6, lane = tid & 63;
  const int qsub = w >> 1, kh = w & 1;
  const int bid = blockIdx.x;
  const int id2 = (bid & 7) * 128 + (bid >> 3);  // XCD swizzle (1024 = 8x128)
  const int h = id2 >> 6, qt = id2 & 63;
  const int lr = lane & 15, lg = lane >> 4;
  const int qrow0 = qt * 64 + qsub * 32;

  const u16* kg = K + (size_t)h * 262144;
  const u16* vg = VT + (size_t)h * 262144;

  // Q B-frags: qf[qg][dg] covers q = qrow0+qg*16+lr, d = dg*32 + lg*8 + [0,8)
  short8 qf[2][2];
#pragma unroll
  for (int qg = 0; qg < 2; ++qg)
#pragma unroll
    for (int dg = 0; dg < 2; ++dg)
      qf[qg][dg] = *(const short8*)(Q + (size_t)h * 262144 +
                                    (size_t)(qrow0 + qg * 16 + lr) * 64 + dg * 32 + lg * 8);

  // stage one 64-key K tile (8KB) for key-half KH into buffer B.
  // source chunk pre-swizzled (c&7)^(row&7); LDS dest linear (rule 21).
#define STAGE1(KH, B, J)                                                      \
  do {                                                                        \
    _Pragma("unroll")                                                         \
    for (int it = 0; it < 2; ++it) {                                          \
      const int c = it * 256 + tid;                                           \
      const int row = c >> 3;                                                 \
      const int sc = (c & 7) ^ (row & 7);                                     \
      const u16* gk = kg + (size_t)((J) + row) * 64 + sc * 8;                 \
      __builtin_amdgcn_global_load_lds(                                       \
          (const __attribute__((address_space(1))) u32*)gk,                   \
          (__attribute__((address_space(3))) u32*)&Ks[KH][B][c * 8], 16, 0, 0); \
    }                                                                         \
  } while (0)
#define STAGE(B, T) do { STAGE1(0, B, (T) * 64); STAGE1(1, B, 2048 + (T) * 64); } while (0)

  f32x4 o[4][2];  // o[dg][qg]: d = dg*16+lg*4+r, q = qg*16+lr
#pragma unroll
  for (int dg = 0; dg < 4; ++dg)
#pragma unroll
    for (int qg = 0; qg < 2; ++qg) o[dg][qg] = fzero();
  float lsum[2] = {0.f, 0.f};

  STAGE(0, 0);
  __syncthreads();

  int b = 0;
  for (int t = 0; t < 32; ++t) {
    if (t < 31) STAGE(b ^ 1, t + 1);
    u32x4 pb[2][2];  // pb[half][qg]: PV B-frags for stored keys half*32 + [0,32)
#pragma unroll
    for (int half = 0; half < 2; ++half) {
      f32x4 s[2][2];  // s[ki][qg]: key = (half*2+ki)*16 + lg*4 + r, q = qg*16+lr
      __builtin_amdgcn_s_setprio(1);
#pragma unroll
      for (int ki = 0; ki < 2; ++ki) {
        const int row = (half * 2 + ki) * 16 + lr;
        const int sw = (row & 7) << 4;
        const char* base = (const char*)&Ks[kh][b][0] + row * 128;
        const short8 k0 = *(const short8*)(base + ((lg * 16) ^ sw));
        const short8 k1 = *(const short8*)(base + ((64 + lg * 16) ^ sw));
#pragma unroll
        for (int qg = 0; qg < 2; ++qg) {
          s[ki][qg] = __builtin_amdgcn_mfma_f32_16x16x32_bf16(k0, qf[qg][0], fzero(), 0, 0, 0);
          s[ki][qg] = __builtin_amdgcn_mfma_f32_16x16x32_bf16(k1, qf[qg][1], s[ki][qg], 0, 0, 0);
        }
      }
      __builtin_amdgcn_s_setprio(0);
#pragma unroll
      for (int qg = 0; qg < 2; ++qg) {
        float rs = 0.f;
#pragma unroll
        for (int ki = 0; ki < 2; ++ki)
#pragma unroll
          for (int r = 0; r < 4; ++r) {
            const float e = EXP2(s[ki][qg][r]);
            s[ki][qg][r] = e;
            rs += e;
          }
        lsum[qg] += rs;
        pb[half][qg][0] = cvtpk(s[0][qg][0], s[0][qg][1]);
        pb[half][qg][1] = cvtpk(s[0][qg][2], s[0][qg][3]);
        pb[half][qg][2] = cvtpk(s[1][qg][0], s[1][qg][1]);
        pb[half][qg][3] = cvtpk(s[1][qg][2], s[1][qg][3]);
      }
    }
    // O^T += V^T P^T; V direct from global, frag-packed (R6-verified):
    // vf slot i = ks*4+dg at vbase + i*512, blk32 = kh*64 + t*2 + ks.
    const u16* vbase = vg + (size_t)(kh * 64 + t * 2) * 2048 + lane * 8;
    __builtin_amdgcn_s_setprio(1);
#pragma unroll
    for (int dg = 0; dg < 4; ++dg) {
      const short8 v0 = *(const short8*)(vbase + dg * 512);
      const short8 v1 = *(const short8*)(vbase + (4 + dg) * 512);
#pragma unroll
      for (int qg = 0; qg < 2; ++qg) {
        o[dg][qg] = __builtin_amdgcn_mfma_f32_16x16x32_bf16(
            v0, __builtin_bit_cast(short8, pb[0][qg]), o[dg][qg], 0, 0, 0);
        o[dg][qg] = __builtin_amdgcn_mfma_f32_16x16x32_bf16(
            v1, __builtin_bit_cast(short8, pb[1][qg]), o[dg][qg], 0, 0, 0);
      }
    }
    __builtin_amdgcn_s_setprio(0);
    __syncthreads();
    b ^= 1;
  }
#undef STAGE
#undef STAGE1

  // reduce lsum across the 4 lane-groups (each holds disjoint key slots)
#pragma unroll
  for (int qg = 0; qg < 2; ++qg) {
    lsum[qg] += __shfl_xor(lsum[qg], 16, 64);
    lsum[qg] += __shfl_xor(lsum[qg], 32, 64);
  }

  // combine the two key-halves through LDS (K staging buffers are retired;
  // cO = 2 qsub x 8 regions x 1KB = 16KB < 32KB)
  float* cO = (float*)&Ks[0][0][0];
  if (kh == 1) {
#pragma unroll
    for (int qg = 0; qg < 2; ++qg) {
#pragma unroll
      for (int dg = 0; dg < 4; ++dg)
        *(f32x4*)(cO + qsub * 2048 + (qg * 4 + dg) * 256 + lane * 4) = o[dg][qg];
      cL[qsub * 32 + qg * 16 + lr] = lsum[qg];  // 4 lanes, same value
    }
  }
  __syncthreads();
  if (kh == 0) {
    const float hs = EXP2(-(float)h * LOG2PHI);  // phi^-h
#pragma unroll
    for (int qg = 0; qg < 2; ++qg) {
      const float l = fmaxf(lsum[qg] + cL[qsub * 32 + qg * 16 + lr], 1e-10f);
      const float sc = hs / l;
#pragma unroll
      for (int dg = 0; dg < 4; ++dg) {
        const f32x4 oth = *(const f32x4*)(cO + qsub * 2048 + (qg * 4 + dg) * 256 + lane * 4);
        u16x4 pk;
#pragma unroll
        for (int r = 0; r < 4; ++r) pk[r] = f2bf((o[dg][qg][r] + oth[r]) * sc);
        *(u16x4*)(O + (size_t)(qrow0 + qg * 16 + lr) * 1024 + h * 64 + dg * 16 + lg * 4) = pk;
      }
    }
  }
}

extern "C" void kernel_launch(void* const* d_in, const int* in_sizes, int n_in,
                              void* d_out, int out_size, void* d_ws, size_t ws_size,
                              hipStream_t stream) {
  const float* x = (const float*)d_in[0];
  const float* Wq = (const float*)d_in[1];
  const float* bq = (const float*)d_in[2];
  const float* Wk = (const float*)d_in[3];
  const float* bk = (const float*)d_in[4];
  const float* Wv = (const float*)d_in[5];
  const float* bv = (const float*)d_in[6];
  const float* Wo = (const float*)d_in[7];
  const float* bo = (const float*)d_in[8];
  float* out = (float*)d_out;

  // ws layout (u16 elems): xb 4M | wqkv 3M | wob 1M | qs 4M | ks 4M | vt 4M
  u16* xb = (u16*)d_ws;
  u16* wqkv = xb + 4194304;
  u16* wob = wqkv + 3145728;
  u16* qs = wob + 1048576;
  u16* ks = qs + 4194304;
  u16* vt = ks + 4194304;
  u16* ob = xb;  // reuse (x dead after QKV GEMM)

  cvt_all<<<8192, 256, 0, stream>>>(x, Wq, Wk, Wv, Wo, xb, wqkv, wob);

  gemm_bt<0, 64><<<dim3(64, 24), 256, 0, stream>>>(xb, wqkv, bq, bk, bv, qs, ks, vt, nullptr);
  attn_kernel<<<1024, 256, 0, stream>>>(qs, ks, vt, ob);
  gemm_bt<1, 64><<<dim3(64, 8), 256, 0, stream>>>(ob, wob, bo, nullptr, nullptr,
                                                  nullptr, nullptr, nullptr, out);
}

// Round 14
// 146.874 us; speedup vs baseline: 1.1864x; 1.1864x over previous
//
#include <hip/hip_runtime.h>

// FractalAttention on gfx950: bf16 MFMA pipeline.  (R11 configuration — best known)
// cvt(fp32->bf16, fused) -> GEMM QKV (64x128 tile -> 1536 blocks, 6/CU) ->
// flash attention (R8 structure: v5 + setprio) -> GEMM O-proj (64x128, 2/CU).

typedef unsigned short u16;
typedef unsigned int u32;
typedef __attribute__((ext_vector_type(8))) short short8;
typedef __attribute__((ext_vector_type(4))) float f32x4;
typedef __attribute__((ext_vector_type(4))) u16 u16x4;
typedef __attribute__((ext_vector_type(4))) u32 u32x4;

#define KDIM 1024
// 0.125 (1/sqrt(64)) * log2(e): fold softmax scale + base-2 conversion into Q
#define QSCALE 0.18033688011112042f
// log2(phi)
#define LOG2PHI 0.6942419136306174f

__device__ __forceinline__ u16 f2bf(float f) {
  u32 u = __builtin_bit_cast(u32, f);
  u32 r = (u + 0x7fffu + ((u >> 16) & 1u)) >> 16;  // RNE
  return (u16)r;
}

__device__ __forceinline__ u32 cvtpk(float lo, float hi) {
  u32 r;
  asm("v_cvt_pk_bf16_f32 %0, %1, %2" : "=v"(r) : "v"(lo), "v"(hi));
  return r;
}

// single v_exp_f32 (exp2f without fast-math lowers to ~8 instrs of ocml fixup)
#define EXP2(x) __builtin_amdgcn_exp2f(x)

__device__ __forceinline__ f32x4 fzero() {
  f32x4 z; z[0] = 0.f; z[1] = 0.f; z[2] = 0.f; z[3] = 0.f; return z;
}

// ---------------- fused fp32 -> bf16 convert (x + 4 weight matrices) ----------------
__global__ __launch_bounds__(256) void cvt_all(
    const float* __restrict__ x, const float* __restrict__ wq,
    const float* __restrict__ wk, const float* __restrict__ wv,
    const float* __restrict__ wo, u16* __restrict__ xb,
    u16* __restrict__ wqkv, u16* __restrict__ wob) {
  const int i = blockIdx.x * 256 + threadIdx.x;
  const float* src;
  u16* dst;
  int off;
  if (i < 1048576) { src = x; dst = xb; off = i; }
  else if (i < 1310720) { src = wq; dst = wqkv; off = i - 1048576; }
  else if (i < 1572864) { src = wk; dst = wqkv + 1048576; off = i - 1310720; }
  else if (i < 1835008) { src = wv; dst = wqkv + 2097152; off = i - 1572864; }
  else { src = wo; dst = wob; off = i - 1835008; }
  f32x4 v = *(const f32x4*)(src + (size_t)off * 4);
  u16x4 o;
  o[0] = f2bf(v[0]); o[1] = f2bf(v[1]); o[2] = f2bf(v[2]); o[3] = f2bf(v[3]);
  *(u16x4*)(dst + (size_t)off * 4) = o;
}

// ---------------- GEMM C = A[M,1024] * B[N,1024]^T (both K-major bf16) ----------------
// MB x 128 tile, BK=64, 4 waves (2x2), each wave (MB/2) x 64 via (MB/32)x4 frags.
// MB=64 for both modes: grid doubles (QKV 1536 = 6/CU, O-proj 512 = 2/CU) so
// co-resident blocks hide the stage-barrier drain.
// MODE 0: QKV epilogue. MODE 1: fp32 out + bias.
template <int MODE, int MB>
__global__ __launch_bounds__(256) void gemm_bt(
    const u16* __restrict__ A, const u16* __restrict__ Bw,
    const float* __restrict__ bias0, const float* __restrict__ bias1,
    const float* __restrict__ bias2,
    u16* __restrict__ qo, u16* __restrict__ ko, u16* __restrict__ vto,
    float* __restrict__ co) {
  __shared__ u16 As[MB * 64];
  __shared__ u16 Bs[128 * 64];
  const int tid = threadIdx.x;
  const int w = tid >> 6, lane = tid & 63;
  const int wr = w >> 1, wc = w & 1;
  const int bm = blockIdx.x, bn = blockIdx.y;
  const int lr = lane & 15, lg = lane >> 4;
  const int srow8 = lane >> 3;   // staging: row within 8-row group
  const int schunk = lane & 7;   // staging: 16B chunk within row
  constexpr int MF = MB / 32;    // A-frags per wave

  f32x4 acc[MF][4];
#pragma unroll
  for (int m = 0; m < MF; ++m)
#pragma unroll
    for (int n = 0; n < 4; ++n) acc[m][n] = fzero();

  for (int kt = 0; kt < KDIM / 64; ++kt) {
    // ---- stage A (MB rows) + B (128 rows): global_load_lds width16, source
    // pre-swizzled (c&7)^(row&7) so swizzled reads see logical layout (rule 21).
#pragma unroll
    for (int it = 0; it < MF; ++it) {
      const int g = w * MF + it;                       // 8-row group, 0..MB/8-1
      const int rowt = g * 8 + srow8;
      const int ck = schunk ^ (rowt & 7);
      const u16* sa = A + (size_t)(bm * MB + rowt) * KDIM + kt * 64 + ck * 8;
      __builtin_amdgcn_global_load_lds(
          (const __attribute__((address_space(1))) u32*)sa,
          (__attribute__((address_space(3))) u32*)&As[g * 512], 16, 0, 0);
    }
#pragma unroll
    for (int it = 0; it < 4; ++it) {
      const int g = w * 4 + it;                        // 0..15
      const int rowt = g * 8 + srow8;
      const int ck = schunk ^ (rowt & 7);
      const u16* sb = Bw + (size_t)(bn * 128 + rowt) * KDIM + kt * 64 + ck * 8;
      __builtin_amdgcn_global_load_lds(
          (const __attribute__((address_space(1))) u32*)sb,
          (__attribute__((address_space(3))) u32*)&Bs[g * 512], 16, 0, 0);
    }
    __syncthreads();
#pragma unroll
    for (int kk = 0; kk < 2; ++kk) {
      short8 af[MF], bf[4];
#pragma unroll
      for (int m = 0; m < MF; ++m) {
        const int row = wr * (MB / 2) + m * 16 + lr;
        const int kb = kk * 64 + lg * 16;
        af[m] = *(const short8*)((const char*)As + row * 128 + (kb ^ ((row & 7) << 4)));
      }
#pragma unroll
      for (int n = 0; n < 4; ++n) {
        const int row = wc * 64 + n * 16 + lr;
        const int kb = kk * 64 + lg * 16;
        bf[n] = *(const short8*)((const char*)Bs + row * 128 + (kb ^ ((row & 7) << 4)));
      }
#pragma unroll
      for (int m = 0; m < MF; ++m)
#pragma unroll
        for (int n = 0; n < 4; ++n)
          acc[m][n] = __builtin_amdgcn_mfma_f32_16x16x32_bf16(af[m], bf[n], acc[m][n], 0, 0, 0);
    }
    __syncthreads();
  }

  // ---- epilogue; C/D layout: row=(lane>>4)*4+reg, col=lane&15
#pragma unroll
  for (int m = 0; m < MF; ++m) {
#pragma unroll
    for (int n = 0; n < 4; ++n) {
#pragma unroll
      for (int r = 0; r < 4; ++r) {
        const int srow = bm * MB + wr * (MB / 2) + m * 16 + lg * 4 + r;
        const int col = bn * 128 + wc * 64 + n * 16 + lr;
        float v = acc[m][n][r];
        if (MODE == 0) {
          const int which = col >> 10;        // 0=q 1=k 2=v
          const int hd = col & 1023;
          const int h = hd >> 6, d = hd & 63;
          const float* bp = (which == 0) ? bias0 : (which == 1) ? bias1 : bias2;
          v += bp[hd];
          if (which == 0) {
            qo[(size_t)h * 262144 + (size_t)srow * 64 + d] = f2bf(v * QSCALE);
          } else if (which == 1) {
            ko[(size_t)h * 262144 + (size_t)srow * 64 + d] = f2bf(v);
          } else {
            // V^T with keys permuted within 32-groups so attention's PV B-frag
            // (kappa from in-lane P order) needs no cross-lane ops:
            // logical key lambda = t*16 + lg*4 + r  ->  stored kappa = lg*8 + (t&1)*4 + r.
            const int k5 = srow & 31;
            const int kap = ((k5 >> 2) & 3) * 8 + ((k5 >> 4) & 1) * 4 + (k5 & 3);
            vto[(size_t)h * 262144 + (size_t)d * 4096 + (srow & ~31) + kap] = f2bf(v);
          }
        } else {
          co[(size_t)srow * 1024 + col] = v + bias0[col];
        }
      }
    }
  }
}

// ---------------- flash attention v8 = v5 (proven 88us) + setprio ----------------
// 512 blocks (XCD-swizzled), 4 waves = 2 qsub x 2 kh, K+V double-buffered LDS,
// no-max softmax (p=exp2(s), shift-invariant, logits bounded), two-phase
// softmax (s[2][4] live range), key halves combined through retired staging LDS.
// Structure verified stable across R8/R10/R11 (88.0 +/- 0.5 us); five
// structural alternatives (R3/R6/R7/R9/R12) all regressed 25-40%.
__global__ __launch_bounds__(256) void attn_kernel(const u16* __restrict__ Q,
                                                   const u16* __restrict__ K,
                                                   const u16* __restrict__ VT,
                                                   u16* __restrict__ O) {
  __shared__ u16 Ks[2][2][4096];  // [khalf][buf][64 keys x 64 d]
  __shared__ u16 Vs[2][2][4096];  // [khalf][buf][64 d x 64 keys']
  const int tid = threadIdx.x;
  const int w = tid >> 6, lane = tid & 63;
  const int qsub = w >> 1, kh = w & 1;
  const int bid = blockIdx.x;
  const int id2 = (bid & 7) * 64 + (bid >> 3);  // XCD swizzle: 2 heads per XCD L2
  const int h = id2 >> 5, qt = id2 & 31;
  const int lr = lane & 15, lg = lane >> 4;
  const int qrow0 = qt * 128 + qsub * 64;

  const u16* kg = K + (size_t)h * 262144;
  const u16* vg = VT + (size_t)h * 262144;

  // Q B-frags: qf[qg][dg] covers q = qrow0+qg*16+lr, d = dg*32 + lg*8 + [0,8)
  short8 qf[4][2];
#pragma unroll
  for (int qg = 0; qg < 4; ++qg)
#pragma unroll
    for (int dg = 0; dg < 2; ++dg)
      qf[qg][dg] = *(const short8*)(Q + (size_t)h * 262144 +
                                    (size_t)(qrow0 + qg * 16 + lr) * 64 + dg * 32 + lg * 8);

  // stage one 64-key tile-set (K 8KB + V 8KB) for key-half KH into buffer B.
  // source chunk pre-swizzled (c&7)^(row&7); LDS dest linear (rule 21).
#define STAGE1(KH, B, J)                                                      \
  do {                                                                        \
    _Pragma("unroll")                                                         \
    for (int it = 0; it < 2; ++it) {                                          \
      const int c = it * 256 + tid;                                           \
      const int row = c >> 3;                                                 \
      const int sc = (c & 7) ^ (row & 7);                                     \
      const u16* gk = kg + (size_t)((J) + row) * 64 + sc * 8;                 \
      __builtin_amdgcn_global_load_lds(                                       \
          (const __attribute__((address_space(1))) u32*)gk,                   \
          (__attribute__((address_space(3))) u32*)&Ks[KH][B][c * 8], 16, 0, 0); \
      const u16* gv = vg + (size_t)row * 4096 + (J) + sc * 8;                 \
      __builtin_amdgcn_global_load_lds(                                       \
          (const __attribute__((address_space(1))) u32*)gv,                   \
          (__attribute__((address_space(3))) u32*)&Vs[KH][B][c * 8], 16, 0, 0); \
    }                                                                         \
  } while (0)
#define STAGE(B, T) do { STAGE1(0, B, (T) * 64); STAGE1(1, B, 2048 + (T) * 64); } while (0)

  f32x4 o[4][4];  // o[dg][qg]: d = dg*16+lg*4+r, q = qg*16+lr
#pragma unroll
  for (int dg = 0; dg < 4; ++dg)
#pragma unroll
    for (int qg = 0; qg < 4; ++qg) o[dg][qg] = fzero();
  float lsum[4] = {0.f, 0.f, 0.f, 0.f};

  STAGE(0, 0);
  __syncthreads();

  int b = 0;
  for (int t = 0; t < 32; ++t) {
    if (t < 31) STAGE(b ^ 1, t + 1);
    u32x4 pb[2][4];  // pb[half][qg]: PV B-frags for stored keys half*32 + [0,32)
#pragma unroll
    for (int half = 0; half < 2; ++half) {
      f32x4 s[2][4];  // s[ki][qg]: key = (half*2+ki)*16 + lg*4 + r, q = qg*16+lr
      __builtin_amdgcn_s_setprio(1);
#pragma unroll
      for (int ki = 0; ki < 2; ++ki) {
        const int row = (half * 2 + ki) * 16 + lr;
        const int sw = (row & 7) << 4;
        const char* base = (const char*)&Ks[kh][b][0] + row * 128;
        const short8 k0 = *(const short8*)(base + ((lg * 16) ^ sw));
        const short8 k1 = *(const short8*)(base + ((64 + lg * 16) ^ sw));
#pragma unroll
        for (int qg = 0; qg < 4; ++qg) {
          s[ki][qg] = __builtin_amdgcn_mfma_f32_16x16x32_bf16(k0, qf[qg][0], fzero(), 0, 0, 0);
          s[ki][qg] = __builtin_amdgcn_mfma_f32_16x16x32_bf16(k1, qf[qg][1], s[ki][qg], 0, 0, 0);
        }
      }
      __builtin_amdgcn_s_setprio(0);
#pragma unroll
      for (int qg = 0; qg < 4; ++qg) {
        float rs = 0.f;
#pragma unroll
        for (int ki = 0; ki < 2; ++ki)
#pragma unroll
          for (int r = 0; r < 4; ++r) {
            const float e = EXP2(s[ki][qg][r]);
            s[ki][qg][r] = e;
            rs += e;
          }
        lsum[qg] += rs;
        pb[half][qg][0] = cvtpk(s[0][qg][0], s[0][qg][1]);
        pb[half][qg][1] = cvtpk(s[0][qg][2], s[0][qg][3]);
        pb[half][qg][2] = cvtpk(s[1][qg][0], s[1][qg][1]);
        pb[half][qg][3] = cvtpk(s[1][qg][2], s[1][qg][3]);
      }
    }
    // O^T += V^T P^T (keys pre-permuted in V^T storage)
    __builtin_amdgcn_s_setprio(1);
#pragma unroll
    for (int dg = 0; dg < 4; ++dg) {
      const int row = dg * 16 + lr;
      const int sw = (row & 7) << 4;
      const char* base = (const char*)&Vs[kh][b][0] + row * 128;
      const short8 v0 = *(const short8*)(base + ((lg * 16) ^ sw));
      const short8 v1 = *(const short8*)(base + ((64 + lg * 16) ^ sw));
#pragma unroll
      for (int qg = 0; qg < 4; ++qg) {
        o[dg][qg] = __builtin_amdgcn_mfma_f32_16x16x32_bf16(
            v0, __builtin_bit_cast(short8, pb[0][qg]), o[dg][qg], 0, 0, 0);
        o[dg][qg] = __builtin_amdgcn_mfma_f32_16x16x32_bf16(
            v1, __builtin_bit_cast(short8, pb[1][qg]), o[dg][qg], 0, 0, 0);
      }
    }
    __builtin_amdgcn_s_setprio(0);
    __syncthreads();
    b ^= 1;
  }
#undef STAGE
#undef STAGE1

  // reduce lsum across the 4 lane-groups (each holds disjoint key slots)
#pragma unroll
  for (int qg = 0; qg < 4; ++qg) {
    lsum[qg] += __shfl_xor(lsum[qg], 16, 64);
    lsum[qg] += __shfl_xor(lsum[qg], 32, 64);
  }

  // combine the two key-halves through LDS (staging buffers are retired)
  float* cO = (float*)&Ks[0][0][0];  // [qsub][(qg*4+dg)*256 + lane*4] -> 32KB
  float* cL = (float*)&Vs[0][0][0];  // [qsub][qg*16 + lr]
  if (kh == 1) {
#pragma unroll
    for (int qg = 0; qg < 4; ++qg) {
#pragma unroll
      for (int dg = 0; dg < 4; ++dg)
        *(f32x4*)(cO + qsub * 4096 + (qg * 4 + dg) * 256 + lane * 4) = o[dg][qg];
      cL[qsub * 64 + qg * 16 + lr] = lsum[qg];  // 4 lanes, same value
    }
  }
  __syncthreads();
  if (kh == 0) {
    const float hs = EXP2(-(float)h * LOG2PHI);  // phi^-h
#pragma unroll
    for (int qg = 0; qg < 4; ++qg) {
      const float l = fmaxf(lsum[qg] + cL[qsub * 64 + qg * 16 + lr], 1e-10f);
      const float sc = hs / l;
#pragma unroll
      for (int dg = 0; dg < 4; ++dg) {
        const f32x4 oth = *(const f32x4*)(cO + qsub * 4096 + (qg * 4 + dg) * 256 + lane * 4);
        u16x4 pk;
#pragma unroll
        for (int r = 0; r < 4; ++r) pk[r] = f2bf((o[dg][qg][r] + oth[r]) * sc);
        *(u16x4*)(O + (size_t)(qrow0 + qg * 16 + lr) * 1024 + h * 64 + dg * 16 + lg * 4) = pk;
      }
    }
  }
}

extern "C" void kernel_launch(void* const* d_in, const int* in_sizes, int n_in,
                              void* d_out, int out_size, void* d_ws, size_t ws_size,
                              hipStream_t stream) {
  const float* x = (const float*)d_in[0];
  const float* Wq = (const float*)d_in[1];
  const float* bq = (const float*)d_in[2];
  const float* Wk = (const float*)d_in[3];
  const float* bk = (const float*)d_in[4];
  const float* Wv = (const float*)d_in[5];
  const float* bv = (const float*)d_in[6];
  const float* Wo = (const float*)d_in[7];
  const float* bo = (const float*)d_in[8];
  float* out = (float*)d_out;

  // ws layout (u16 elems): xb 4M | wqkv 3M | wob 1M | qs 4M | ks 4M | vt 4M
  u16* xb = (u16*)d_ws;
  u16* wqkv = xb + 4194304;
  u16* wob = wqkv + 3145728;
  u16* qs = wob + 1048576;
  u16* ks = qs + 4194304;
  u16* vt = ks + 4194304;
  u16* ob = xb;  // reuse (x dead after QKV GEMM)

  cvt_all<<<8192, 256, 0, stream>>>(x, Wq, Wk, Wv, Wo, xb, wqkv, wob);

  gemm_bt<0, 64><<<dim3(64, 24), 256, 0, stream>>>(xb, wqkv, bq, bk, bv, qs, ks, vt, nullptr);
  attn_kernel<<<512, 256, 0, stream>>>(qs, ks, vt, ob);
  gemm_bt<1, 64><<<dim3(64, 8), 256, 0, stream>>>(ob, wob, bo, nullptr, nullptr,
                                                  nullptr, nullptr, nullptr, out);
}